// Round 6
// baseline (344.479 us; speedup 1.0000x reference)
//
#include <hip/hip_runtime.h>
#include <math.h>

#define NN 50000
#define NE 800000
#define GB 391   // (NN+127)/128 row-tiles of 128

typedef __attribute__((ext_vector_type(8))) short short8;
typedef __attribute__((ext_vector_type(4))) float floatx4;

#define AS1 __attribute__((address_space(1)))
#define AS3 __attribute__((address_space(3)))

__device__ __forceinline__ unsigned short f2bf(float f) {
    unsigned u = __float_as_uint(f);
    unsigned r = (u + 0x7fff + ((u >> 16) & 1)) >> 16;
    return (unsigned short)r;
}
__device__ __forceinline__ float bf2f(unsigned short h) {
    return __uint_as_float(((unsigned)h) << 16);
}

// ---------------- CSR build ----------------

__global__ void k_scan_part(const int* __restrict__ deg, int* __restrict__ partials) {
    __shared__ int s[1024];
    int idx = blockIdx.x * 1024 + threadIdx.x;
    s[threadIdx.x] = (idx < NN) ? deg[idx] : 0;
    for (int off = 512; off > 0; off >>= 1) {
        __syncthreads();
        if (threadIdx.x < off) s[threadIdx.x] += s[threadIdx.x + off];
    }
    if (threadIdx.x == 0) partials[blockIdx.x] = s[0];
}

// single wave: prefix-scan up to 64 partials
__global__ void k_scan_top(int* __restrict__ partials, int* __restrict__ row_start, int n) {
    int lane = threadIdx.x;
    int orig = (lane < n) ? partials[lane] : 0;
    int v = orig;
    for (int off = 1; off < 64; off <<= 1) {
        int u = __shfl_up(v, off, 64);
        if (lane >= off) v += u;
    }
    if (lane < n) partials[lane] = v - orig;   // exclusive
    if (lane == 63) row_start[NN] = v;         // grand total
}

__global__ void k_scan_final(const int* __restrict__ deg, const int* __restrict__ partials,
                             int* __restrict__ row_start) {
    __shared__ int s[1024];
    int idx = blockIdx.x * 1024 + threadIdx.x;
    int v = (idx < NN) ? deg[idx] : 0;
    s[threadIdx.x] = v;
    for (int off = 1; off < 1024; off <<= 1) {
        __syncthreads();
        int tmp = (threadIdx.x >= off) ? s[threadIdx.x - off] : 0;
        __syncthreads();
        s[threadIdx.x] += tmp;
    }
    if (idx < NN) row_start[idx] = partials[blockIdx.x] + s[threadIdx.x] - v;
}

__global__ void k_scatter(const int* __restrict__ src, const int* __restrict__ dst,
                          const int* __restrict__ row_start, int* __restrict__ cursor,
                          int* __restrict__ col_idx) {
    int e = blockIdx.x * blockDim.x + threadIdx.x;
    if (e < NE) {
        int d = dst[e];
        int slot = atomicAdd(&cursor[d], 1);
        col_idx[row_start[d] + slot] = src[e];
    }
}

// ---------------- prep: cvt (h->bf16) | hist | packW, one launch ----------------

__global__ __launch_bounds__(256)
void k_prep(const float* __restrict__ h, unsigned short* __restrict__ hB,
            const int* __restrict__ dst, int* __restrict__ deg,
            const float* w0, const float* w1, const float* w2, const float* w3,
            const float* w4, const float* w5, const float* w6, const float* w7,
            short* __restrict__ wpk) {
    int bid = blockIdx.x;
    if (bid < 3125) {              // cvt
        int i = (bid * 256 + threadIdx.x) * 8;
        float4 a = *(const float4*)&h[i];
        float4 b = *(const float4*)&h[i + 4];
        short8 v;
        v[0] = (short)f2bf(a.x); v[1] = (short)f2bf(a.y);
        v[2] = (short)f2bf(a.z); v[3] = (short)f2bf(a.w);
        v[4] = (short)f2bf(b.x); v[5] = (short)f2bf(b.y);
        v[6] = (short)f2bf(b.z); v[7] = (short)f2bf(b.w);
        *(short8*)&hB[i] = v;
    } else if (bid < 6250) {       // hist
        int e = (bid - 3125) * 256 + threadIdx.x;
        if (e < NE) atomicAdd(&deg[dst[e]], 1);
    } else {                       // packW, 8 blocks
        int wb = bid - 6250;
        const float* W;
        switch (wb) {
            case 0: W = w0; break; case 1: W = w1; break;
            case 2: W = w2; break; case 3: W = w3; break;
            case 4: W = w4; break; case 5: W = w5; break;
            case 6: W = w6; break; default: W = w7; break;
        }
        short* dstp = wpk + (size_t)wb * 16384;
#pragma unroll
        for (int i = 0; i < 8; ++i) {
            int q = threadIdx.x + i * 256;
            int cb = q >> 8, ks = (q >> 6) & 3, lane = q & 63;
            int n = lane & 15, g = lane >> 4;
            int col = cb * 16 + n, krow = ks * 32 + g * 8;
            short8 v;
#pragma unroll
            for (int j = 0; j < 8; ++j)
                v[j] = (short)f2bf(W[(krow + j) * 128 + col]);
            *(short8*)&dstp[q * 8] = v;
        }
    }
}

// ---------------- mean aggregation (wave per node, bf16 feats) ----------------

__global__ __launch_bounds__(256)
void k_agg(const unsigned short* __restrict__ feat, const int* __restrict__ row_start,
           const int* __restrict__ col_idx, unsigned short* __restrict__ outp) {
    int node = (blockIdx.x * 256 + threadIdx.x) >> 6;
    int lane = threadIdx.x & 63;
    if (node >= NN) return;
    const int beg = row_start[node], end = row_start[node + 1];
    const size_t lo = (size_t)(lane * 2);
    float sx = 0.f, sy = 0.f;
    int j = beg;
#pragma unroll 1
    for (; j + 8 <= end; j += 8) {
        int s[8];
#pragma unroll
        for (int u = 0; u < 8; ++u) s[u] = col_idx[j + u];
        unsigned v[8];
#pragma unroll
        for (int u = 0; u < 8; ++u)
            v[u] = *(const unsigned*)&feat[(size_t)s[u] * 128 + lo];
#pragma unroll
        for (int u = 0; u < 8; ++u) {
            sx += bf2f((unsigned short)(v[u] & 0xffff));
            sy += bf2f((unsigned short)(v[u] >> 16));
        }
    }
#pragma unroll 1
    for (; j < end; ++j) {
        int s = col_idx[j];
        unsigned v = *(const unsigned*)&feat[(size_t)s * 128 + lo];
        sx += bf2f((unsigned short)(v & 0xffff));
        sy += bf2f((unsigned short)(v >> 16));
    }
    float inv = 1.0f / fmaxf((float)(end - beg), 1.0f);
    unsigned o = (unsigned)f2bf(sx * inv) | ((unsigned)f2bf(sy * inv) << 16);
    *(unsigned*)&outp[(size_t)node * 128 + lo] = o;
}

// ---------------- MFMA GEMM building blocks ----------------
// tile 128 rows x 128 cols per 256-thr block; wave = 32 rows (2 frags).
// A-fragments loaded DIRECTLY global->VGPR (no LDS); W staged in LDS (32 KB).

struct AF { short8 v[2][4]; };   // [row-frag][k-slot]

template<int F32>
__device__ __forceinline__ AF load_af(const void* Ap, int row0, int wv, int lane) {
    AF a;
    const int m = lane & 15, g = lane >> 4;
#pragma unroll
    for (int f = 0; f < 2; ++f) {
        int r = row0 + wv * 32 + f * 16 + m;
        if (r >= NN) r = NN - 1;
        if (!F32) {
            const unsigned short* p = (const unsigned short*)Ap + (size_t)r * 128 + g * 8;
#pragma unroll
            for (int ks = 0; ks < 4; ++ks)
                a.v[f][ks] = *(const short8*)(p + ks * 32);
        } else {
            const float* p = (const float*)Ap + (size_t)r * 128 + g * 8;
#pragma unroll
            for (int ks = 0; ks < 4; ++ks) {
                float4 x = *(const float4*)(p + ks * 32);
                float4 y = *(const float4*)(p + ks * 32 + 4);
                short8 t;
                t[0] = (short)f2bf(x.x); t[1] = (short)f2bf(x.y);
                t[2] = (short)f2bf(x.z); t[3] = (short)f2bf(x.w);
                t[4] = (short)f2bf(y.x); t[5] = (short)f2bf(y.y);
                t[6] = (short)f2bf(y.z); t[7] = (short)f2bf(y.w);
                a.v[f][ks] = t;
            }
        }
    }
    return a;
}

__device__ __forceinline__ void stage_w(const short* Wc, short* sW, int wv, int lane) {
#pragma unroll
    for (int i = 0; i < 8; ++i) {
        int cbase = (i * 4 + wv) * 64;
        __builtin_amdgcn_global_load_lds(
            (const AS1 unsigned int*)(Wc + (size_t)(cbase + lane) * 8),
            (AS3 unsigned int*)(sW + cbase * 8), 16, 0, 0);
    }
}

__device__ __forceinline__ void drain_barrier() {
    asm volatile("s_waitcnt vmcnt(0)" ::: "memory");
    __builtin_amdgcn_sched_barrier(0);
    __syncthreads();
}

__device__ __forceinline__ void mfma_all(const AF& a, const short* sW, int lane,
                                         floatx4 acc0[8], floatx4 acc1[8]) {
#pragma unroll
    for (int ks = 0; ks < 4; ++ks)
#pragma unroll
        for (int cb = 0; cb < 8; ++cb) {
            short8 bf = *(const short8*)&sW[((cb * 4 + ks) * 64 + lane) * 8];
            acc0[cb] = __builtin_amdgcn_mfma_f32_16x16x32_bf16(a.v[0][ks], bf, acc0[cb], 0, 0, 0);
            acc1[cb] = __builtin_amdgcn_mfma_f32_16x16x32_bf16(a.v[1][ks], bf, acc1[cb], 0, 0, 0);
        }
}

// epilogue: C/D layout col=lane&15, row=(lane>>4)*4+reg
template<int ELU, int OUTF32, int RESID>
__device__ __forceinline__ void store_out(void* outv, const unsigned short* HS,
                                          const float* bias, int row0, int wv, int lane,
                                          floatx4 acc0[8], floatx4 acc1[8]) {
    const int m = lane & 15, g = lane >> 4;
    const int rowbase = row0 + wv * 32 + g * 4;
#pragma unroll
    for (int f = 0; f < 2; ++f)
#pragma unroll
        for (int cb = 0; cb < 8; ++cb) {
            int C = cb * 16 + m;
            float bb = bias[C];
#pragma unroll
            for (int rr = 0; rr < 4; ++rr) {
                int R = rowbase + f * 16 + rr;
                if (R < NN) {
                    float v = (f ? acc1[cb][rr] : acc0[cb][rr]) + bb;
                    if (ELU) v = (v > 0.f) ? v : expm1f(v);
                    size_t idx = (size_t)R * 128 + C;
                    if (OUTF32) {
                        if (RESID) v += bf2f(HS[idx]);
                        ((float*)outv)[idx] = v;
                    } else {
                        ((unsigned short*)outv)[idx] = f2bf(v);
                    }
                }
            }
        }
}

#define ACC_INIT \
    floatx4 acc0[8], acc1[8]; \
    _Pragma("unroll") \
    for (int cb = 0; cb < 8; ++cb) { \
        acc0[cb] = (floatx4){0.f, 0.f, 0.f, 0.f}; \
        acc1[cb] = (floatx4){0.f, 0.f, 0.f, 0.f}; \
    }

// ---------------- GEMM kernels ----------------

// blocks [0,GB): X1 = ELU(hB@Wself1 + AG@Wneigh1 + bc)   (bf16)
// blocks [GB,2GB): S1 = ELU(hB@Wsk1 + bsk1)              (f32, into d_out scratch)
__global__ __launch_bounds__(256)
void k_g1(const unsigned short* __restrict__ hB, const unsigned short* __restrict__ AG,
          const short* __restrict__ WpSelf, const short* __restrict__ WpNeigh,
          const short* __restrict__ WpSk1, const float* __restrict__ bc,
          const float* __restrict__ bsk1, unsigned short* __restrict__ X1,
          float* __restrict__ S1) {
    __shared__ short sW[16384];
    const int t = threadIdx.x, wv = t >> 6, lane = t & 63;
    ACC_INIT;
    if (blockIdx.x < GB) {
        const int row0 = blockIdx.x * 128;
        AF a1 = load_af<0>(hB, row0, wv, lane);
        AF a2 = load_af<0>(AG, row0, wv, lane);
        stage_w(WpSelf, sW, wv, lane);
        drain_barrier();
        mfma_all(a1, sW, lane, acc0, acc1);
        __syncthreads();
        stage_w(WpNeigh, sW, wv, lane);
        drain_barrier();
        mfma_all(a2, sW, lane, acc0, acc1);
        store_out<1, 0, 0>(X1, nullptr, bc, row0, wv, lane, acc0, acc1);
    } else {
        const int row0 = (blockIdx.x - GB) * 128;
        AF a = load_af<0>(hB, row0, wv, lane);
        stage_w(WpSk1, sW, wv, lane);
        drain_barrier();
        mfma_all(a, sW, lane, acc0, acc1);
        store_out<1, 1, 0>(S1, nullptr, bsk1, row0, wv, lane, acc0, acc1);
    }
}

// blocks [0,GB): Y1 = ELU(X1@Wsi1 + bs1)   (bf16)
// blocks [GB,2GB): HS = S1@Wsk2 + bsk2     (f32 in -> bf16 out)
__global__ __launch_bounds__(256)
void k_g2(const unsigned short* __restrict__ X1, const float* __restrict__ S1,
          const short* __restrict__ WpSi1, const short* __restrict__ WpSk2,
          const float* __restrict__ bs1, const float* __restrict__ bsk2,
          unsigned short* __restrict__ Y1, unsigned short* __restrict__ HS) {
    __shared__ short sW[16384];
    const int t = threadIdx.x, wv = t >> 6, lane = t & 63;
    ACC_INIT;
    if (blockIdx.x < GB) {
        const int row0 = blockIdx.x * 128;
        AF a = load_af<0>(X1, row0, wv, lane);
        stage_w(WpSi1, sW, wv, lane);
        drain_barrier();
        mfma_all(a, sW, lane, acc0, acc1);
        store_out<1, 0, 0>(Y1, nullptr, bs1, row0, wv, lane, acc0, acc1);
    } else {
        const int row0 = (blockIdx.x - GB) * 128;
        AF a = load_af<1>(S1, row0, wv, lane);
        stage_w(WpSk2, sW, wv, lane);
        drain_barrier();
        mfma_all(a, sW, lane, acc0, acc1);
        store_out<0, 0, 0>(HS, nullptr, bsk2, row0, wv, lane, acc0, acc1);
    }
}

// X3 = ELU(Y1@Wsi2 + bs2)  (bf16)
__global__ __launch_bounds__(256)
void k_g3(const unsigned short* __restrict__ Y1, const short* __restrict__ WpSi2,
          const float* __restrict__ bs2, unsigned short* __restrict__ X3) {
    __shared__ short sW[16384];
    const int t = threadIdx.x, wv = t >> 6, lane = t & 63;
    const int row0 = blockIdx.x * 128;
    ACC_INIT;
    AF a = load_af<0>(Y1, row0, wv, lane);
    stage_w(WpSi2, sW, wv, lane);
    drain_barrier();
    mfma_all(a, sW, lane, acc0, acc1);
    store_out<1, 0, 0>(X3, nullptr, bs2, row0, wv, lane, acc0, acc1);
}

// out = X3@Wself2 + AG2@Wneigh2 + b + HS   (f32)
__global__ __launch_bounds__(256)
void k_g4(const unsigned short* __restrict__ X3, const unsigned short* __restrict__ AG2,
          const unsigned short* __restrict__ HS, const short* __restrict__ WpSelf,
          const short* __restrict__ WpNeigh, const float* __restrict__ bias,
          float* __restrict__ out) {
    __shared__ short sW[16384];
    const int t = threadIdx.x, wv = t >> 6, lane = t & 63;
    const int row0 = blockIdx.x * 128;
    ACC_INIT;
    AF a1 = load_af<0>(X3, row0, wv, lane);
    AF a2 = load_af<0>(AG2, row0, wv, lane);
    stage_w(WpSelf, sW, wv, lane);
    drain_barrier();
    mfma_all(a1, sW, lane, acc0, acc1);
    __syncthreads();
    stage_w(WpNeigh, sW, wv, lane);
    drain_barrier();
    mfma_all(a2, sW, lane, acc0, acc1);
    store_out<0, 1, 1>(out, HS, bias, row0, wv, lane, acc0, acc1);
}

// ---------------- launch ----------------

extern "C" void kernel_launch(void* const* d_in, const int* in_sizes, int n_in,
                              void* d_out, int out_size, void* d_ws, size_t ws_size,
                              hipStream_t stream) {
    const float* h        = (const float*)d_in[0];
    const int*   src      = (const int*)d_in[1];
    const int*   dst      = (const int*)d_in[2];
    const float* W_skip1  = (const float*)d_in[3];
    const float* b_skip1  = (const float*)d_in[4];
    const float* W_skip2  = (const float*)d_in[5];
    const float* b_skip2  = (const float*)d_in[6];
    const float* W_self1  = (const float*)d_in[7];
    const float* W_neigh1 = (const float*)d_in[8];
    const float* b_conv1  = (const float*)d_in[9];
    const float* W_si1    = (const float*)d_in[10];
    const float* b_si1    = (const float*)d_in[11];
    const float* W_si2    = (const float*)d_in[12];
    const float* b_si2    = (const float*)d_in[13];
    const float* W_self2  = (const float*)d_in[14];
    const float* W_neigh2 = (const float*)d_in[15];
    const float* b_conv2  = (const float*)d_in[16];
    float* out = (float*)d_out;

    char* ws = (char*)d_ws;
    int* deg       = (int*)ws;            // [50048]
    int* cursor    = deg + 50048;         // [50048]
    int* row_start = deg + 100096;        // [50001] (padded region to 150208)
    int* partials  = deg + 150208;        // [64]
    int* col_idx   = deg + 150272;        // [800000]  -> ends at byte 3801088
    short* wpk          = (short*)(ws + 3801088);            // 8 x 16384 bf16 = 256 KB
    unsigned short* hB  = (unsigned short*)(ws + 4063232);   // 6.4M bf16 (h -> Y1 -> AG2)
    unsigned short* B1  = (unsigned short*)(ws + 16863232);  // 6.4M bf16 (X1 -> X3)
    unsigned short* B2  = (unsigned short*)(ws + 29663232);  // 6.4M bf16 (AG1 -> HS)

    hipMemsetAsync(ws, 0, 100096 * sizeof(int), stream);

    // cvt | hist | packW in one launch
    k_prep<<<6258, 256, 0, stream>>>(h, hB, dst, deg,
                                     W_skip1, W_skip2, W_self1, W_neigh1,
                                     W_si1, W_si2, W_self2, W_neigh2, wpk);
    k_scan_part<<<49, 1024, 0, stream>>>(deg, partials);
    k_scan_top<<<1, 64, 0, stream>>>(partials, row_start, 49);
    k_scan_final<<<49, 1024, 0, stream>>>(deg, partials, row_start);
    k_scatter<<<(NE + 255) / 256, 256, 0, stream>>>(src, dst, row_start, cursor, col_idx);

    // AG1 = mean-agg(hB) -> B2
    k_agg<<<12500, 256, 0, stream>>>(hB, row_start, col_idx, B2);

    // conv1(dual) || skip1 : X1 -> B1, S1(f32) -> out
    k_g1<<<2 * GB, 256, 0, stream>>>(hB, B2, wpk + 2 * 16384, wpk + 3 * 16384, wpk,
                                     b_conv1, b_skip1, B1, out);

    // si1 || skip2 : Y1 -> hB, HS -> B2
    k_g2<<<2 * GB, 256, 0, stream>>>(B1, out, wpk + 4 * 16384, wpk + 16384,
                                     b_si1, b_skip2, hB, B2);

    // si2 : X3 -> B1
    k_g3<<<GB, 256, 0, stream>>>(hB, wpk + 5 * 16384, b_si2, B1);

    // AG2 = mean-agg(X3) -> hB
    k_agg<<<12500, 256, 0, stream>>>(B1, row_start, col_idx, hB);

    // conv2(dual) + residual -> out
    k_g4<<<GB, 256, 0, stream>>>(B1, hB, B2, wpk + 6 * 16384, wpk + 7 * 16384,
                                 b_conv2, out);
}

// Round 7
// 314.204 us; speedup vs baseline: 1.0964x; 1.0964x over previous
//
#include <hip/hip_runtime.h>
#include <math.h>

#define NN 50000
#define NE 800000
#define GB 391   // (NN+127)/128 row-tiles of 128

typedef __attribute__((ext_vector_type(8))) short short8;
typedef __attribute__((ext_vector_type(4))) float floatx4;

#define AS1 __attribute__((address_space(1)))
#define AS3 __attribute__((address_space(3)))

__device__ __forceinline__ unsigned short f2bf(float f) {
    unsigned u = __float_as_uint(f);
    unsigned r = (u + 0x7fff + ((u >> 16) & 1)) >> 16;
    return (unsigned short)r;
}
__device__ __forceinline__ float bf2f(unsigned short h) {
    return __uint_as_float(((unsigned)h) << 16);
}

// ---------------- CSR build ----------------

__global__ void k_scan_part(const int* __restrict__ deg, int* __restrict__ partials) {
    __shared__ int s[1024];
    int idx = blockIdx.x * 1024 + threadIdx.x;
    s[threadIdx.x] = (idx < NN) ? deg[idx] : 0;
    for (int off = 512; off > 0; off >>= 1) {
        __syncthreads();
        if (threadIdx.x < off) s[threadIdx.x] += s[threadIdx.x + off];
    }
    if (threadIdx.x == 0) partials[blockIdx.x] = s[0];
}

__global__ void k_scan_top(int* __restrict__ partials, int* __restrict__ row_start, int n) {
    int lane = threadIdx.x;
    int orig = (lane < n) ? partials[lane] : 0;
    int v = orig;
    for (int off = 1; off < 64; off <<= 1) {
        int u = __shfl_up(v, off, 64);
        if (lane >= off) v += u;
    }
    if (lane < n) partials[lane] = v - orig;   // exclusive
    if (lane == 63) row_start[NN] = v;         // grand total
}

__global__ void k_scan_final(const int* __restrict__ deg, const int* __restrict__ partials,
                             int* __restrict__ row_start) {
    __shared__ int s[1024];
    int idx = blockIdx.x * 1024 + threadIdx.x;
    int v = (idx < NN) ? deg[idx] : 0;
    s[threadIdx.x] = v;
    for (int off = 1; off < 1024; off <<= 1) {
        __syncthreads();
        int tmp = (threadIdx.x >= off) ? s[threadIdx.x - off] : 0;
        __syncthreads();
        s[threadIdx.x] += tmp;
    }
    if (idx < NN) row_start[idx] = partials[blockIdx.x] + s[threadIdx.x] - v;
}

__global__ void k_scatter(const int* __restrict__ src, const int* __restrict__ dst,
                          const int* __restrict__ row_start, int* __restrict__ cursor,
                          int* __restrict__ col_idx) {
    int e = blockIdx.x * blockDim.x + threadIdx.x;
    if (e < NE) {
        int d = dst[e];
        int slot = atomicAdd(&cursor[d], 1);
        col_idx[row_start[d] + slot] = src[e];
    }
}

// ---------------- prep: cvt (h->bf16) | hist | packW, one launch ----------------

__global__ __launch_bounds__(256)
void k_prep(const float* __restrict__ h, unsigned short* __restrict__ hB,
            const int* __restrict__ dst, int* __restrict__ deg,
            const float* w0, const float* w1, const float* w2, const float* w3,
            const float* w4, const float* w5, const float* w6, const float* w7,
            short* __restrict__ wpk) {
    int bid = blockIdx.x;
    if (bid < 3125) {              // cvt
        int i = (bid * 256 + threadIdx.x) * 8;
        float4 a = *(const float4*)&h[i];
        float4 b = *(const float4*)&h[i + 4];
        short8 v;
        v[0] = (short)f2bf(a.x); v[1] = (short)f2bf(a.y);
        v[2] = (short)f2bf(a.z); v[3] = (short)f2bf(a.w);
        v[4] = (short)f2bf(b.x); v[5] = (short)f2bf(b.y);
        v[6] = (short)f2bf(b.z); v[7] = (short)f2bf(b.w);
        *(short8*)&hB[i] = v;
    } else if (bid < 6250) {       // hist
        int e = (bid - 3125) * 256 + threadIdx.x;
        if (e < NE) atomicAdd(&deg[dst[e]], 1);
    } else {                       // packW, 8 blocks
        int wb = bid - 6250;
        const float* W;
        switch (wb) {
            case 0: W = w0; break; case 1: W = w1; break;
            case 2: W = w2; break; case 3: W = w3; break;
            case 4: W = w4; break; case 5: W = w5; break;
            case 6: W = w6; break; default: W = w7; break;
        }
        short* dstp = wpk + (size_t)wb * 16384;
#pragma unroll
        for (int i = 0; i < 8; ++i) {
            int q = threadIdx.x + i * 256;
            int cb = q >> 8, ks = (q >> 6) & 3, lane = q & 63;
            int n = lane & 15, g = lane >> 4;
            int col = cb * 16 + n, krow = ks * 32 + g * 8;
            short8 v;
#pragma unroll
            for (int j = 0; j < 8; ++j)
                v[j] = (short)f2bf(W[(krow + j) * 128 + col]);
            *(short8*)&dstp[q * 8] = v;
        }
    }
}

// ---------------- mean aggregation (wave per node, bf16 feats) ----------------

__global__ __launch_bounds__(256)
void k_agg(const unsigned short* __restrict__ feat, const int* __restrict__ row_start,
           const int* __restrict__ col_idx, unsigned short* __restrict__ outp) {
    int node = (blockIdx.x * 256 + threadIdx.x) >> 6;
    int lane = threadIdx.x & 63;
    if (node >= NN) return;
    const int beg = row_start[node], end = row_start[node + 1];
    const size_t lo = (size_t)(lane * 2);
    float sx = 0.f, sy = 0.f;
    int j = beg;
#pragma unroll 1
    for (; j + 8 <= end; j += 8) {
        int s[8];
#pragma unroll
        for (int u = 0; u < 8; ++u) s[u] = col_idx[j + u];
        unsigned v[8];
#pragma unroll
        for (int u = 0; u < 8; ++u)
            v[u] = *(const unsigned*)&feat[(size_t)s[u] * 128 + lo];
#pragma unroll
        for (int u = 0; u < 8; ++u) {
            sx += bf2f((unsigned short)(v[u] & 0xffff));
            sy += bf2f((unsigned short)(v[u] >> 16));
        }
    }
#pragma unroll 1
    for (; j < end; ++j) {
        int s = col_idx[j];
        unsigned v = *(const unsigned*)&feat[(size_t)s * 128 + lo];
        sx += bf2f((unsigned short)(v & 0xffff));
        sy += bf2f((unsigned short)(v >> 16));
    }
    float inv = 1.0f / fmaxf((float)(end - beg), 1.0f);
    unsigned o = (unsigned)f2bf(sx * inv) | ((unsigned)f2bf(sy * inv) << 16);
    *(unsigned*)&outp[(size_t)node * 128 + lo] = o;
}

// ---------------- MFMA GEMM building blocks ----------------
// tile 128 rows x 128 cols, 256 thr = 4 waves, wave = 32 rows (2 frags).
// sMem: [0,16384) shorts = sW (prepacked W chunks, linear)
//       [16384,32768) shorts = sA (row r, slot c holds global chunk c^(r&7))

__device__ __forceinline__ void stage_w(const short* Wc, short* sW, int wv, int lane) {
#pragma unroll
    for (int i = 0; i < 8; ++i) {
        int cbase = (i * 4 + wv) * 64;
        __builtin_amdgcn_global_load_lds(
            (const AS1 unsigned int*)(Wc + (size_t)(cbase + lane) * 8),
            (AS3 unsigned int*)(sW + cbase * 8), 16, 0, 0);
    }
}

__device__ __forceinline__ void stage_a(const unsigned short* Ac, short* sA, int row0,
                                        int wv, int lane) {
#pragma unroll
    for (int i = 0; i < 8; ++i) {
        int cbase = (i * 4 + wv) * 64;
        int id = cbase + lane;
        int r = id >> 4, cs = id & 15;
        int rg = row0 + r; if (rg >= NN) rg = NN - 1;
        int csrc = cs ^ (r & 7);
        __builtin_amdgcn_global_load_lds(
            (const AS1 unsigned int*)(Ac + (size_t)rg * 128 + csrc * 8),
            (AS3 unsigned int*)(sA + cbase * 8), 16, 0, 0);
    }
}

__device__ __forceinline__ void drain_barrier() {
    asm volatile("s_waitcnt vmcnt(0)" ::: "memory");
    __builtin_amdgcn_sched_barrier(0);
    __syncthreads();
}

__device__ __forceinline__ void mm_tile(const short* sA, const short* sW, int wv, int lane,
                                        floatx4 acc0[8], floatx4 acc1[8]) {
    const int m = lane & 15, g = lane >> 4;
    const int r0 = wv * 32;
#pragma unroll
    for (int ks = 0; ks < 4; ++ks) {
        int cxor = (ks * 4 + g) ^ (m & 7);
        short8 af0 = *(const short8*)&sA[((r0 + m) * 16 + cxor) * 8];
        short8 af1 = *(const short8*)&sA[((r0 + 16 + m) * 16 + cxor) * 8];
#pragma unroll
        for (int cb = 0; cb < 8; ++cb) {
            short8 bf = *(const short8*)&sW[((cb * 4 + ks) * 64 + lane) * 8];
            acc0[cb] = __builtin_amdgcn_mfma_f32_16x16x32_bf16(af0, bf, acc0[cb], 0, 0, 0);
            acc1[cb] = __builtin_amdgcn_mfma_f32_16x16x32_bf16(af1, bf, acc1[cb], 0, 0, 0);
        }
    }
}

#define ACC_INIT \
    floatx4 acc0[8], acc1[8]; \
    _Pragma("unroll") \
    for (int cb = 0; cb < 8; ++cb) { \
        acc0[cb] = (floatx4){0.f, 0.f, 0.f, 0.f}; \
        acc1[cb] = (floatx4){0.f, 0.f, 0.f, 0.f}; \
    }

// ---- coalesced epilogues: acc -> LDS (skewed) -> vectorized global stores ----
// bf16: uses sA region (32KB), col skew = (C + Rl*8) & 127 (16B-aligned chunks)

template<int ELU>
__device__ __forceinline__ void epi_bf16(short* sEp, unsigned short* gout,
                                         const float* bias, int row0, int wv, int lane,
                                         floatx4 acc0[8], floatx4 acc1[8]) {
    const int m = lane & 15, g = lane >> 4;
    const int t = wv * 64 + lane;
    // phase 1: wave-local scatter into own 32-row LDS slice
#pragma unroll
    for (int f = 0; f < 2; ++f)
#pragma unroll
        for (int cb = 0; cb < 8; ++cb) {
            int C = cb * 16 + m;
            float bb = bias[C];
#pragma unroll
            for (int rr = 0; rr < 4; ++rr) {
                int Rl = wv * 32 + f * 16 + g * 4 + rr;
                float v = (f ? acc1[cb][rr] : acc0[cb][rr]) + bb;
                if (ELU) v = (v > 0.f) ? v : expm1f(v);
                int cs = (C + Rl * 8) & 127;
                sEp[Rl * 128 + cs] = (short)f2bf(v);
            }
        }
    __syncthreads();
    // phase 2: 8 x 16B contiguous per thread -> wave writes 1KB runs
#pragma unroll
    for (int i = 0; i < 8; ++i) {
        int flat = i * 2048 + t * 8;
        int r = flat >> 7, c = flat & 127;
        int cs = (c + r * 8) & 127;
        short8 v = *(const short8*)&sEp[r * 128 + cs];
        int R = row0 + r;
        if (R < NN) *(short8*)&gout[(size_t)R * 128 + c] = v;
    }
}

// f32 (+optional bf16 residual): uses full 64KB (sW+sA), skew = (C + Rl*4) & 127
template<int RESID>
__device__ __forceinline__ void epi_f32(float* sF, float* gout, const unsigned short* HS,
                                        const float* bias, int row0, int wv, int lane,
                                        floatx4 acc0[8], floatx4 acc1[8]) {
    const int m = lane & 15, g = lane >> 4;
    const int t = wv * 64 + lane;
    __syncthreads();   // all waves done reading sW before overwrite
#pragma unroll
    for (int f = 0; f < 2; ++f)
#pragma unroll
        for (int cb = 0; cb < 8; ++cb) {
            int C = cb * 16 + m;
            float bb = bias[C];
#pragma unroll
            for (int rr = 0; rr < 4; ++rr) {
                int Rl = wv * 32 + f * 16 + g * 4 + rr;
                int cs = (C + Rl * 4) & 127;
                sF[Rl * 128 + cs] = (f ? acc1[cb][rr] : acc0[cb][rr]) + bb;
            }
        }
    __syncthreads();
#pragma unroll
    for (int i = 0; i < 16; ++i) {
        int flat = i * 1024 + t * 4;
        int r = flat >> 7, c = flat & 127;
        int cs = (c + r * 4) & 127;
        float4 v = *(const float4*)&sF[r * 128 + cs];
        int R = row0 + r;
        if (R < NN) {
            size_t gi = (size_t)R * 128 + c;
            if (RESID) {
                v.x += bf2f(HS[gi]);     v.y += bf2f(HS[gi + 1]);
                v.z += bf2f(HS[gi + 2]); v.w += bf2f(HS[gi + 3]);
            }
            *(float4*)&gout[gi] = v;
        }
    }
}

// ---------------- GEMM kernels ----------------

// [0,GB): X1 = ELU(hB@Wself1 + AG@Wneigh1 + bc) -> B1
// [GB,2GB): S1 = ELU(hB@Wsk1 + bsk1) -> bf16 scratch in d_out
__global__ __launch_bounds__(256)
void k_g1(const unsigned short* __restrict__ hB, const unsigned short* __restrict__ AG,
          const short* __restrict__ WpSelf, const short* __restrict__ WpNeigh,
          const short* __restrict__ WpSk1, const float* __restrict__ bc,
          const float* __restrict__ bsk1, unsigned short* __restrict__ X1,
          unsigned short* __restrict__ S1) {
    __shared__ short sMem[32768];
    short* sW = sMem;
    short* sA = sMem + 16384;
    const int t = threadIdx.x, wv = t >> 6, lane = t & 63;
    ACC_INIT;
    if (blockIdx.x < GB) {
        const int row0 = blockIdx.x * 128;
        stage_a(hB, sA, row0, wv, lane);
        stage_w(WpSelf, sW, wv, lane);
        drain_barrier();
        mm_tile(sA, sW, wv, lane, acc0, acc1);
        __syncthreads();
        stage_a(AG, sA, row0, wv, lane);
        stage_w(WpNeigh, sW, wv, lane);
        drain_barrier();
        mm_tile(sA, sW, wv, lane, acc0, acc1);
        epi_bf16<1>(sA, X1, bc, row0, wv, lane, acc0, acc1);
    } else {
        const int row0 = (blockIdx.x - GB) * 128;
        stage_a(hB, sA, row0, wv, lane);
        stage_w(WpSk1, sW, wv, lane);
        drain_barrier();
        mm_tile(sA, sW, wv, lane, acc0, acc1);
        epi_bf16<1>(sA, S1, bsk1, row0, wv, lane, acc0, acc1);
    }
}

// [0,GB): Y1 = ELU(X1@Wsi1 + bs1) -> hB
// [GB,2GB): HS = S1@Wsk2 + bsk2 -> B2
__global__ __launch_bounds__(256)
void k_g2(const unsigned short* __restrict__ X1, const unsigned short* __restrict__ S1,
          const short* __restrict__ WpSi1, const short* __restrict__ WpSk2,
          const float* __restrict__ bs1, const float* __restrict__ bsk2,
          unsigned short* __restrict__ Y1, unsigned short* __restrict__ HS) {
    __shared__ short sMem[32768];
    short* sW = sMem;
    short* sA = sMem + 16384;
    const int t = threadIdx.x, wv = t >> 6, lane = t & 63;
    ACC_INIT;
    if (blockIdx.x < GB) {
        const int row0 = blockIdx.x * 128;
        stage_a(X1, sA, row0, wv, lane);
        stage_w(WpSi1, sW, wv, lane);
        drain_barrier();
        mm_tile(sA, sW, wv, lane, acc0, acc1);
        epi_bf16<1>(sA, Y1, bs1, row0, wv, lane, acc0, acc1);
    } else {
        const int row0 = (blockIdx.x - GB) * 128;
        stage_a(S1, sA, row0, wv, lane);
        stage_w(WpSk2, sW, wv, lane);
        drain_barrier();
        mm_tile(sA, sW, wv, lane, acc0, acc1);
        epi_bf16<0>(sA, HS, bsk2, row0, wv, lane, acc0, acc1);
    }
}

// X3 = ELU(Y1@Wsi2 + bs2) -> B1
__global__ __launch_bounds__(256)
void k_g3(const unsigned short* __restrict__ Y1, const short* __restrict__ WpSi2,
          const float* __restrict__ bs2, unsigned short* __restrict__ X3) {
    __shared__ short sMem[32768];
    short* sW = sMem;
    short* sA = sMem + 16384;
    const int t = threadIdx.x, wv = t >> 6, lane = t & 63;
    const int row0 = blockIdx.x * 128;
    ACC_INIT;
    stage_a(Y1, sA, row0, wv, lane);
    stage_w(WpSi2, sW, wv, lane);
    drain_barrier();
    mm_tile(sA, sW, wv, lane, acc0, acc1);
    epi_bf16<1>(sA, X3, bs2, row0, wv, lane, acc0, acc1);
}

// out = X3@Wself2 + AG2@Wneigh2 + b + HS   (f32, coalesced residual read)
__global__ __launch_bounds__(256)
void k_g4(const unsigned short* __restrict__ X3, const unsigned short* __restrict__ AG2,
          const unsigned short* __restrict__ HS, const short* __restrict__ WpSelf,
          const short* __restrict__ WpNeigh, const float* __restrict__ bias,
          float* __restrict__ out) {
    __shared__ short sMem[32768];
    short* sW = sMem;
    short* sA = sMem + 16384;
    const int t = threadIdx.x, wv = t >> 6, lane = t & 63;
    const int row0 = blockIdx.x * 128;
    ACC_INIT;
    stage_a(X3, sA, row0, wv, lane);
    stage_w(WpSelf, sW, wv, lane);
    drain_barrier();
    mm_tile(sA, sW, wv, lane, acc0, acc1);
    __syncthreads();
    stage_a(AG2, sA, row0, wv, lane);
    stage_w(WpNeigh, sW, wv, lane);
    drain_barrier();
    mm_tile(sA, sW, wv, lane, acc0, acc1);
    epi_f32<1>((float*)sMem, out, HS, bias, row0, wv, lane, acc0, acc1);
}

// ---------------- launch ----------------

extern "C" void kernel_launch(void* const* d_in, const int* in_sizes, int n_in,
                              void* d_out, int out_size, void* d_ws, size_t ws_size,
                              hipStream_t stream) {
    const float* h        = (const float*)d_in[0];
    const int*   src      = (const int*)d_in[1];
    const int*   dst      = (const int*)d_in[2];
    const float* W_skip1  = (const float*)d_in[3];
    const float* b_skip1  = (const float*)d_in[4];
    const float* W_skip2  = (const float*)d_in[5];
    const float* b_skip2  = (const float*)d_in[6];
    const float* W_self1  = (const float*)d_in[7];
    const float* W_neigh1 = (const float*)d_in[8];
    const float* b_conv1  = (const float*)d_in[9];
    const float* W_si1    = (const float*)d_in[10];
    const float* b_si1    = (const float*)d_in[11];
    const float* W_si2    = (const float*)d_in[12];
    const float* b_si2    = (const float*)d_in[13];
    const float* W_self2  = (const float*)d_in[14];
    const float* W_neigh2 = (const float*)d_in[15];
    const float* b_conv2  = (const float*)d_in[16];
    float* out = (float*)d_out;

    char* ws = (char*)d_ws;
    int* deg       = (int*)ws;            // [50048]
    int* cursor    = deg + 50048;         // [50048]
    int* row_start = deg + 100096;        // [50001] (padded region to 150208)
    int* partials  = deg + 150208;        // [64]
    int* col_idx   = deg + 150272;        // [800000]  -> ends at byte 3801088
    short* wpk          = (short*)(ws + 3801088);            // 8 x 16384 bf16 = 256 KB
    unsigned short* hB  = (unsigned short*)(ws + 4063232);   // 6.4M bf16 (h -> Y1 -> AG2)
    unsigned short* B1  = (unsigned short*)(ws + 16863232);  // 6.4M bf16 (X1 -> X3)
    unsigned short* B2  = (unsigned short*)(ws + 29663232);  // 6.4M bf16 (AG1 -> HS)
    unsigned short* S1s = (unsigned short*)d_out;            // 12.8 MB bf16 scratch (first half)

    hipMemsetAsync(ws, 0, 100096 * sizeof(int), stream);

    k_prep<<<6258, 256, 0, stream>>>(h, hB, dst, deg,
                                     W_skip1, W_skip2, W_self1, W_neigh1,
                                     W_si1, W_si2, W_self2, W_neigh2, wpk);
    k_scan_part<<<49, 1024, 0, stream>>>(deg, partials);
    k_scan_top<<<1, 64, 0, stream>>>(partials, row_start, 49);
    k_scan_final<<<49, 1024, 0, stream>>>(deg, partials, row_start);
    k_scatter<<<(NE + 255) / 256, 256, 0, stream>>>(src, dst, row_start, cursor, col_idx);

    // AG1 = mean-agg(hB) -> B2
    k_agg<<<12500, 256, 0, stream>>>(hB, row_start, col_idx, B2);

    // conv1(dual) || skip1
    k_g1<<<2 * GB, 256, 0, stream>>>(hB, B2, wpk + 2 * 16384, wpk + 3 * 16384, wpk,
                                     b_conv1, b_skip1, B1, S1s);

    // si1 || skip2
    k_g2<<<2 * GB, 256, 0, stream>>>(B1, S1s, wpk + 4 * 16384, wpk + 16384,
                                     b_si1, b_skip2, hB, B2);

    // si2
    k_g3<<<GB, 256, 0, stream>>>(hB, wpk + 5 * 16384, b_si2, B1);

    // AG2 = mean-agg(X3) -> hB
    k_agg<<<12500, 256, 0, stream>>>(B1, row_start, col_idx, hB);

    // conv2(dual) + residual -> out
    k_g4<<<GB, 256, 0, stream>>>(B1, hB, B2, wpk + 6 * 16384, wpk + 7 * 16384,
                                 b_conv2, out);
}

// Round 8
// 274.917 us; speedup vs baseline: 1.2530x; 1.1429x over previous
//
#include <hip/hip_runtime.h>
#include <math.h>

#define NN 50000
#define NE 800000
#define NRT 782          // row tiles of 64
#define NT  (NRT * 2)    // x 2 col-halves = blocks per GEMM

typedef __attribute__((ext_vector_type(8))) short short8;
typedef __attribute__((ext_vector_type(4))) float floatx4;

#define AS1 __attribute__((address_space(1)))
#define AS3 __attribute__((address_space(3)))

__device__ __forceinline__ unsigned short f2bf(float f) {
    unsigned u = __float_as_uint(f);
    unsigned r = (u + 0x7fff + ((u >> 16) & 1)) >> 16;
    return (unsigned short)r;
}
__device__ __forceinline__ float bf2f(unsigned short h) {
    return __uint_as_float(((unsigned)h) << 16);
}

// ---------------- CSR build ----------------

__global__ void k_hist(const int* __restrict__ dst, int* __restrict__ deg) {
    int e = blockIdx.x * blockDim.x + threadIdx.x;
    if (e < NE) atomicAdd(&deg[dst[e]], 1);
}

__global__ void k_scan_part(const int* __restrict__ deg, int* __restrict__ partials) {
    __shared__ int s[1024];
    int idx = blockIdx.x * 1024 + threadIdx.x;
    s[threadIdx.x] = (idx < NN) ? deg[idx] : 0;
    for (int off = 512; off > 0; off >>= 1) {
        __syncthreads();
        if (threadIdx.x < off) s[threadIdx.x] += s[threadIdx.x + off];
    }
    if (threadIdx.x == 0) partials[blockIdx.x] = s[0];
}

__global__ void k_scan_top(int* __restrict__ partials, int* __restrict__ row_start, int n) {
    int lane = threadIdx.x;
    int orig = (lane < n) ? partials[lane] : 0;
    int v = orig;
    for (int off = 1; off < 64; off <<= 1) {
        int u = __shfl_up(v, off, 64);
        if (lane >= off) v += u;
    }
    if (lane < n) partials[lane] = v - orig;   // exclusive
    if (lane == 63) row_start[NN] = v;         // grand total
}

__global__ void k_scan_final(const int* __restrict__ deg, const int* __restrict__ partials,
                             int* __restrict__ row_start) {
    __shared__ int s[1024];
    int idx = blockIdx.x * 1024 + threadIdx.x;
    int v = (idx < NN) ? deg[idx] : 0;
    s[threadIdx.x] = v;
    for (int off = 1; off < 1024; off <<= 1) {
        __syncthreads();
        int tmp = (threadIdx.x >= off) ? s[threadIdx.x - off] : 0;
        __syncthreads();
        s[threadIdx.x] += tmp;
    }
    if (idx < NN) row_start[idx] = partials[blockIdx.x] + s[threadIdx.x] - v;
}

__global__ void k_scatter(const int* __restrict__ src, const int* __restrict__ dst,
                          const int* __restrict__ row_start, int* __restrict__ cursor,
                          int* __restrict__ col_idx) {
    int e = blockIdx.x * blockDim.x + threadIdx.x;
    if (e < NE) {
        int d = dst[e];
        int slot = atomicAdd(&cursor[d], 1);
        col_idx[row_start[d] + slot] = src[e];
    }
}

// ---------------- f32 -> bf16 convert ----------------

__global__ __launch_bounds__(256)
void k_cvt(const float* __restrict__ src, unsigned short* __restrict__ dst) {
    int i = (blockIdx.x * 256 + threadIdx.x) * 8;
    float4 a = *(const float4*)&src[i];
    float4 b = *(const float4*)&src[i + 4];
    short8 v;
    v[0] = (short)f2bf(a.x); v[1] = (short)f2bf(a.y);
    v[2] = (short)f2bf(a.z); v[3] = (short)f2bf(a.w);
    v[4] = (short)f2bf(b.x); v[5] = (short)f2bf(b.y);
    v[6] = (short)f2bf(b.z); v[7] = (short)f2bf(b.w);
    *(short8*)&dst[i] = v;
}

// ---------------- pack W (f32 [128][128]) into MFMA-B bf16 layout ----------------
// chunk q = (cb*4 + ks)*64 + lane, lane = n + 16*g: holds W[ks*32+g*8+j][cb*16+n], j=0..7

__global__ __launch_bounds__(256)
void k_packW(const float* w0, const float* w1, const float* w2, const float* w3,
             const float* w4, const float* w5, const float* w6, const float* w7,
             short* __restrict__ wpk) {
    const float* W;
    switch (blockIdx.x) {
        case 0: W = w0; break; case 1: W = w1; break;
        case 2: W = w2; break; case 3: W = w3; break;
        case 4: W = w4; break; case 5: W = w5; break;
        case 6: W = w6; break; default: W = w7; break;
    }
    short* dst = wpk + (size_t)blockIdx.x * 16384;
#pragma unroll
    for (int i = 0; i < 8; ++i) {
        int q = threadIdx.x + i * 256;
        int cb = q >> 8, ks = (q >> 6) & 3, lane = q & 63;
        int n = lane & 15, g = lane >> 4;
        int col = cb * 16 + n, krow = ks * 32 + g * 8;
        short8 v;
#pragma unroll
        for (int j = 0; j < 8; ++j)
            v[j] = (short)f2bf(W[(krow + j) * 128 + col]);
        *(short8*)&dst[q * 8] = v;
    }
}

// ---------------- mean aggregation (wave per node, bf16 feats) ----------------

__global__ __launch_bounds__(256)
void k_agg(const unsigned short* __restrict__ feat, const int* __restrict__ row_start,
           const int* __restrict__ col_idx, unsigned short* __restrict__ outp) {
    int node = (blockIdx.x * 256 + threadIdx.x) >> 6;
    int lane = threadIdx.x & 63;
    if (node >= NN) return;
    const int beg = row_start[node], end = row_start[node + 1];
    const size_t lo = (size_t)(lane * 2);
    float sx = 0.f, sy = 0.f;
    int j = beg;
#pragma unroll 1
    for (; j + 8 <= end; j += 8) {
        int s[8];
#pragma unroll
        for (int u = 0; u < 8; ++u) s[u] = col_idx[j + u];
        unsigned v[8];
#pragma unroll
        for (int u = 0; u < 8; ++u)
            v[u] = *(const unsigned*)&feat[(size_t)s[u] * 128 + lo];
#pragma unroll
        for (int u = 0; u < 8; ++u) {
            sx += bf2f((unsigned short)(v[u] & 0xffff));
            sy += bf2f((unsigned short)(v[u] >> 16));
        }
    }
#pragma unroll 1
    for (; j < end; ++j) {
        int s = col_idx[j];
        unsigned v = *(const unsigned*)&feat[(size_t)s * 128 + lo];
        sx += bf2f((unsigned short)(v & 0xffff));
        sy += bf2f((unsigned short)(v >> 16));
    }
    float inv = 1.0f / fmaxf((float)(end - beg), 1.0f);
    unsigned o = (unsigned)f2bf(sx * inv) | ((unsigned)f2bf(sy * inv) << 16);
    *(unsigned*)&outp[(size_t)node * 128 + lo] = o;
}

// ---------------- MFMA GEMM: out = f(A@W [+ A2@W2] + b [+ out]) ----------------
// tile 64 rows x 64 cols; 256 thr = 4 waves; wave = 16 rows x 64 cols.
// grid = NRT row-tiles x 2 col-halves = 1564 blocks (~6/CU, 5 resident @32KB LDS).

template<int DUAL, int DOELU, int OUTF32, int DOADD>
__global__ __launch_bounds__(256)
void k_mm(const unsigned short* __restrict__ A, const unsigned short* __restrict__ A2,
          const short* __restrict__ Wp, const short* __restrict__ Wp2,
          const float* __restrict__ bias, void* outv) {
    __shared__ short sW[8192];   // 16 KB: 1024 chunks (4 cb x 4 ks x 64 lanes), linear
    __shared__ short sA[8192];   // 16 KB: 64 rows x 16 chunk-slots; slot c holds chunk c^(r&7)
    const int t = threadIdx.x;
    const int wv = t >> 6, lane = t & 63;
    const int rb = blockIdx.x >> 1, ct = blockIdx.x & 1;
    const int row0 = rb * 64;
    const int col0 = ct * 64;
    const int m = lane & 15, g = lane >> 4;

    floatx4 acc[4];
#pragma unroll
    for (int cb = 0; cb < 4; ++cb) acc[cb] = (floatx4){0.f, 0.f, 0.f, 0.f};

    const int npass = DUAL ? 2 : 1;
    for (int pass = 0; pass < npass; ++pass) {
        const unsigned short* Ac = pass ? A2 : A;
        const short* Wc = (pass ? Wp2 : Wp) + ct * 8192;   // col-half of packed W
        __syncthreads();
        // stage W: 1024 x 16B, linear
#pragma unroll
        for (int i = 0; i < 4; ++i) {
            int cbase = (i * 4 + wv) * 64;
            __builtin_amdgcn_global_load_lds(
                (const AS1 unsigned int*)(Wc + (size_t)(cbase + lane) * 8),
                (AS3 unsigned int*)(sW + cbase * 8), 16, 0, 0);
        }
        // stage A: 1024 x 16B; LDS slot (r,c) <- global chunk (r, c^(r&7))
#pragma unroll
        for (int i = 0; i < 4; ++i) {
            int cbase = (i * 4 + wv) * 64;
            int id = cbase + lane;
            int r = id >> 4, cs = id & 15;
            int rg = row0 + r; if (rg >= NN) rg = NN - 1;
            int csrc = cs ^ (r & 7);
            __builtin_amdgcn_global_load_lds(
                (const AS1 unsigned int*)(Ac + (size_t)rg * 128 + csrc * 8),
                (AS3 unsigned int*)(sA + cbase * 8), 16, 0, 0);
        }
        // drain hedge: LDS-visibility of global_load_lds unconditional
        asm volatile("s_waitcnt vmcnt(0)" ::: "memory");
        __builtin_amdgcn_sched_barrier(0);
        __syncthreads();

        const int r0 = wv * 16;
#pragma unroll
        for (int ks = 0; ks < 4; ++ks) {
            int cxor = (ks * 4 + g) ^ (m & 7);
            short8 af = *(const short8*)&sA[((r0 + m) * 16 + cxor) * 8];
#pragma unroll
            for (int cb = 0; cb < 4; ++cb) {
                short8 bf = *(const short8*)&sW[((cb * 4 + ks) * 64 + lane) * 8];
                acc[cb] = __builtin_amdgcn_mfma_f32_16x16x32_bf16(af, bf, acc[cb], 0, 0, 0);
            }
        }
    }

    // epilogue: C/D layout col=lane&15, row=(lane>>4)*4+reg
    const int rowbase = row0 + wv * 16 + g * 4;
#pragma unroll
    for (int cb = 0; cb < 4; ++cb) {
        int C = col0 + cb * 16 + m;
        float bb = bias[C];
#pragma unroll
        for (int rr = 0; rr < 4; ++rr) {
            int R = rowbase + rr;
            if (R < NN) {
                float v = acc[cb][rr] + bb;
                if (DOELU) v = (v > 0.f) ? v : expm1f(v);
                if (OUTF32) {
                    float* o = (float*)outv;
                    size_t idx = (size_t)R * 128 + C;
                    if (DOADD) v += o[idx];
                    o[idx] = v;
                } else {
                    unsigned short* o = (unsigned short*)outv;
                    o[(size_t)R * 128 + C] = f2bf(v);
                }
            }
        }
    }
}

// ---------------- launch ----------------

extern "C" void kernel_launch(void* const* d_in, const int* in_sizes, int n_in,
                              void* d_out, int out_size, void* d_ws, size_t ws_size,
                              hipStream_t stream) {
    const float* h        = (const float*)d_in[0];
    const int*   src      = (const int*)d_in[1];
    const int*   dst      = (const int*)d_in[2];
    const float* W_skip1  = (const float*)d_in[3];
    const float* b_skip1  = (const float*)d_in[4];
    const float* W_skip2  = (const float*)d_in[5];
    const float* b_skip2  = (const float*)d_in[6];
    const float* W_self1  = (const float*)d_in[7];
    const float* W_neigh1 = (const float*)d_in[8];
    const float* b_conv1  = (const float*)d_in[9];
    const float* W_si1    = (const float*)d_in[10];
    const float* b_si1    = (const float*)d_in[11];
    const float* W_si2    = (const float*)d_in[12];
    const float* b_si2    = (const float*)d_in[13];
    const float* W_self2  = (const float*)d_in[14];
    const float* W_neigh2 = (const float*)d_in[15];
    const float* b_conv2  = (const float*)d_in[16];
    float* out = (float*)d_out;

    char* ws = (char*)d_ws;
    int* deg       = (int*)ws;            // [50048]
    int* cursor    = deg + 50048;         // [50048]
    int* row_start = deg + 100096;        // [50001] (padded region to 150208)
    int* partials  = deg + 150208;        // [64]
    int* col_idx   = deg + 150272;        // [800000]  -> ends at byte 3801088
    short* wpk          = (short*)(ws + 3801088);            // 8 x 16384 bf16 = 256 KB
    unsigned short* hB  = (unsigned short*)(ws + 4063232);   // 6.4M bf16
    unsigned short* B1  = (unsigned short*)(ws + 16863232);  // 6.4M bf16
    unsigned short* B2  = (unsigned short*)(ws + 29663232);  // 6.4M bf16

    hipMemsetAsync(ws, 0, 100096 * sizeof(int), stream);

    k_hist<<<(NE + 255) / 256, 256, 0, stream>>>(dst, deg);
    k_scan_part<<<49, 1024, 0, stream>>>(deg, partials);
    k_scan_top<<<1, 64, 0, stream>>>(partials, row_start, 49);
    k_scan_final<<<49, 1024, 0, stream>>>(deg, partials, row_start);
    k_scatter<<<(NE + 255) / 256, 256, 0, stream>>>(src, dst, row_start, cursor, col_idx);

    k_packW<<<8, 256, 0, stream>>>(W_skip1, W_skip2, W_self1, W_neigh1,
                                   W_si1, W_si2, W_self2, W_neigh2, wpk);
    k_cvt<<<3125, 256, 0, stream>>>(h, hB);

    // h_skip: B1 = ELU(h@Ws1+b); out = B1@Ws2+b
    k_mm<0, 1, 0, 0><<<NT, 256, 0, stream>>>(hB, nullptr, wpk, nullptr, b_skip1, B1);
    k_mm<0, 0, 1, 0><<<NT, 256, 0, stream>>>(B1, nullptr, wpk + 16384, nullptr, b_skip2, out);

    // SAGE 1: B2 = agg(hB); B1 = ELU(hB@Wself1 + B2@Wneigh1 + b)
    k_agg<<<(NN * 64) / 256 + 1, 256, 0, stream>>>(hB, row_start, col_idx, B2);
    k_mm<1, 1, 0, 0><<<NT, 256, 0, stream>>>(hB, B2, wpk + 2 * 16384, wpk + 3 * 16384, b_conv1, B1);

    // self-interaction: B2 = ELU(B1@Wsi1+b); B1 = ELU(B2@Wsi2+b)
    k_mm<0, 1, 0, 0><<<NT, 256, 0, stream>>>(B1, nullptr, wpk + 4 * 16384, nullptr, b_si1, B2);
    k_mm<0, 1, 0, 0><<<NT, 256, 0, stream>>>(B2, nullptr, wpk + 5 * 16384, nullptr, b_si2, B1);

    // SAGE 2 + residual: B2 = agg(B1); out += B1@Wself2 + B2@Wneigh2 + b
    k_agg<<<(NN * 64) / 256 + 1, 256, 0, stream>>>(B1, row_start, col_idx, B2);
    k_mm<1, 0, 1, 1><<<NT, 256, 0, stream>>>(B1, B2, wpk + 6 * 16384, wpk + 7 * 16384, b_conv2, out);
}

// Round 9
// 252.113 us; speedup vs baseline: 1.3664x; 1.0904x over previous
//
#include <hip/hip_runtime.h>
#include <math.h>

#define NN 50000
#define NE 800000
#define NRT 782          // row tiles of 64
#define NT  (NRT * 2)    // x2 col-halves = 1564 blocks per GEMM
#define SB  3125         // scatter blocks (NE/256)

typedef __attribute__((ext_vector_type(8))) short short8;
typedef __attribute__((ext_vector_type(4))) float floatx4;

#define AS1 __attribute__((address_space(1)))
#define AS3 __attribute__((address_space(3)))

__device__ __forceinline__ unsigned short f2bf(float f) {
    unsigned u = __float_as_uint(f);
    unsigned r = (u + 0x7fff + ((u >> 16) & 1)) >> 16;
    return (unsigned short)r;
}
__device__ __forceinline__ float bf2f(unsigned short h) {
    return __uint_as_float(((unsigned)h) << 16);
}

// ---------------- CSR scans ----------------

__global__ void k_scan_part(const int* __restrict__ deg, int* __restrict__ partials) {
    __shared__ int s[1024];
    int idx = blockIdx.x * 1024 + threadIdx.x;
    s[threadIdx.x] = (idx < NN) ? deg[idx] : 0;
    for (int off = 512; off > 0; off >>= 1) {
        __syncthreads();
        if (threadIdx.x < off) s[threadIdx.x] += s[threadIdx.x + off];
    }
    if (threadIdx.x == 0) partials[blockIdx.x] = s[0];
}

__global__ void k_scan_top(int* __restrict__ partials, int* __restrict__ row_start, int n) {
    int lane = threadIdx.x;
    int orig = (lane < n) ? partials[lane] : 0;
    int v = orig;
    for (int off = 1; off < 64; off <<= 1) {
        int u = __shfl_up(v, off, 64);
        if (lane >= off) v += u;
    }
    if (lane < n) partials[lane] = v - orig;   // exclusive
    if (lane == 63) row_start[NN] = v;
}

__global__ void k_scan_final(const int* __restrict__ deg, const int* __restrict__ partials,
                             int* __restrict__ row_start) {
    __shared__ int s[1024];
    int idx = blockIdx.x * 1024 + threadIdx.x;
    int v = (idx < NN) ? deg[idx] : 0;
    s[threadIdx.x] = v;
    for (int off = 1; off < 1024; off <<= 1) {
        __syncthreads();
        int tmp = (threadIdx.x >= off) ? s[threadIdx.x - off] : 0;
        __syncthreads();
        s[threadIdx.x] += tmp;
    }
    if (idx < NN) row_start[idx] = partials[blockIdx.x] + s[threadIdx.x] - v;
}

// ---------------- prep: cvt (h->bf16) | hist | packW ----------------

__global__ __launch_bounds__(256)
void k_prep(const float* __restrict__ h, unsigned short* __restrict__ hB,
            const int* __restrict__ dst, int* __restrict__ deg,
            const float* w0, const float* w1, const float* w2, const float* w3,
            const float* w4, const float* w5, const float* w6, const float* w7,
            short* __restrict__ wpk) {
    int bid = blockIdx.x;
    if (bid < 3125) {              // cvt
        int i = (bid * 256 + threadIdx.x) * 8;
        float4 a = *(const float4*)&h[i];
        float4 b = *(const float4*)&h[i + 4];
        short8 v;
        v[0] = (short)f2bf(a.x); v[1] = (short)f2bf(a.y);
        v[2] = (short)f2bf(a.z); v[3] = (short)f2bf(a.w);
        v[4] = (short)f2bf(b.x); v[5] = (short)f2bf(b.y);
        v[6] = (short)f2bf(b.z); v[7] = (short)f2bf(b.w);
        *(short8*)&hB[i] = v;
    } else if (bid < 6250) {       // hist
        int e = (bid - 3125) * 256 + threadIdx.x;
        if (e < NE) atomicAdd(&deg[dst[e]], 1);
    } else {                       // packW, 8 blocks
        int wb = bid - 6250;
        const float* W;
        switch (wb) {
            case 0: W = w0; break; case 1: W = w1; break;
            case 2: W = w2; break; case 3: W = w3; break;
            case 4: W = w4; break; case 5: W = w5; break;
            case 6: W = w6; break; default: W = w7; break;
        }
        short* dstp = wpk + (size_t)wb * 16384;
#pragma unroll
        for (int i = 0; i < 8; ++i) {
            int q = threadIdx.x + i * 256;
            int cb = q >> 8, ks = (q >> 6) & 3, lane = q & 63;
            int n = lane & 15, g = lane >> 4;
            int col = cb * 16 + n, krow = ks * 32 + g * 8;
            short8 v;
#pragma unroll
            for (int j = 0; j < 8; ++j)
                v[j] = (short)f2bf(W[(krow + j) * 128 + col]);
            *(short8*)&dstp[q * 8] = v;
        }
    }
}

// ---------------- mean aggregation (wave per node, bf16 feats) ----------------

__global__ __launch_bounds__(256)
void k_agg(const unsigned short* __restrict__ feat, const int* __restrict__ row_start,
           const int* __restrict__ col_idx, unsigned short* __restrict__ outp) {
    int node = (blockIdx.x * 256 + threadIdx.x) >> 6;
    int lane = threadIdx.x & 63;
    if (node >= NN) return;
    const int beg = row_start[node], end = row_start[node + 1];
    const size_t lo = (size_t)(lane * 2);
    float sx = 0.f, sy = 0.f;
    int j = beg;
#pragma unroll 1
    for (; j + 8 <= end; j += 8) {
        int s[8];
#pragma unroll
        for (int u = 0; u < 8; ++u) s[u] = col_idx[j + u];
        unsigned v[8];
#pragma unroll
        for (int u = 0; u < 8; ++u)
            v[u] = *(const unsigned*)&feat[(size_t)s[u] * 128 + lo];
#pragma unroll
        for (int u = 0; u < 8; ++u) {
            sx += bf2f((unsigned short)(v[u] & 0xffff));
            sy += bf2f((unsigned short)(v[u] >> 16));
        }
    }
#pragma unroll 1
    for (; j < end; ++j) {
        int s = col_idx[j];
        unsigned v = *(const unsigned*)&feat[(size_t)s * 128 + lo];
        sx += bf2f((unsigned short)(v & 0xffff));
        sy += bf2f((unsigned short)(v >> 16));
    }
    float inv = 1.0f / fmaxf((float)(end - beg), 1.0f);
    unsigned o = (unsigned)f2bf(sx * inv) | ((unsigned)f2bf(sy * inv) << 16);
    *(unsigned*)&outp[(size_t)node * 128 + lo] = o;
}

// ---------------- GEMM body: 64x64 tile, 4 waves, wave = 16 rows ----------------
// sW 16KB (1024 chunks linear, col-half of packed W); sA 16KB (64 rows x 16 slots,
// slot c holds global chunk c^(r&7)). ADDBF: elementwise += bf16[R*128+C] pre-ELU.

template<int DUAL, int DOELU, int OUTF32, int NOBIAS, int ADDBF>
__device__ __forceinline__ void gemm_body(
        int bid,
        const unsigned short* __restrict__ A, const unsigned short* __restrict__ A2,
        const short* __restrict__ Wp, const short* __restrict__ Wp2,
        const float* __restrict__ bias, const unsigned short* __restrict__ addbf,
        void* outv, short* sW, short* sA) {
    const int t = threadIdx.x;
    const int wv = t >> 6, lane = t & 63;
    const int rb = bid >> 1, ct = bid & 1;
    const int row0 = rb * 64, col0 = ct * 64;
    const int m = lane & 15, g = lane >> 4;

    floatx4 acc[4];
#pragma unroll
    for (int cb = 0; cb < 4; ++cb) acc[cb] = (floatx4){0.f, 0.f, 0.f, 0.f};

    const int npass = DUAL ? 2 : 1;
    for (int pass = 0; pass < npass; ++pass) {
        const unsigned short* Ac = pass ? A2 : A;
        const short* Wc = (pass ? Wp2 : Wp) + ct * 8192;   // col-half of packed W
        __syncthreads();
#pragma unroll
        for (int i = 0; i < 4; ++i) {   // stage W: 1024 x 16B linear
            int cbase = (i * 4 + wv) * 64;
            __builtin_amdgcn_global_load_lds(
                (const AS1 unsigned int*)(Wc + (size_t)(cbase + lane) * 8),
                (AS3 unsigned int*)(sW + cbase * 8), 16, 0, 0);
        }
#pragma unroll
        for (int i = 0; i < 4; ++i) {   // stage A: swizzled source
            int cbase = (i * 4 + wv) * 64;
            int id = cbase + lane;
            int r = id >> 4, cs = id & 15;
            int rg = row0 + r; if (rg >= NN) rg = NN - 1;
            int csrc = cs ^ (r & 7);
            __builtin_amdgcn_global_load_lds(
                (const AS1 unsigned int*)(Ac + (size_t)rg * 128 + csrc * 8),
                (AS3 unsigned int*)(sA + cbase * 8), 16, 0, 0);
        }
        asm volatile("s_waitcnt vmcnt(0)" ::: "memory");
        __builtin_amdgcn_sched_barrier(0);
        __syncthreads();

        const int r0 = wv * 16;
#pragma unroll
        for (int ks = 0; ks < 4; ++ks) {
            int cxor = (ks * 4 + g) ^ (m & 7);
            short8 af = *(const short8*)&sA[((r0 + m) * 16 + cxor) * 8];
#pragma unroll
            for (int cb = 0; cb < 4; ++cb) {
                short8 bf = *(const short8*)&sW[((cb * 4 + ks) * 64 + lane) * 8];
                acc[cb] = __builtin_amdgcn_mfma_f32_16x16x32_bf16(af, bf, acc[cb], 0, 0, 0);
            }
        }
    }

    // epilogue: C/D layout col=lane&15, row=(lane>>4)*4+reg
    const int rowbase = row0 + wv * 16 + g * 4;
#pragma unroll
    for (int cb = 0; cb < 4; ++cb) {
        int C = col0 + cb * 16 + m;
        float bb = NOBIAS ? 0.f : bias[C];
#pragma unroll
        for (int rr = 0; rr < 4; ++rr) {
            int R = rowbase + rr;
            if (R < NN) {
                size_t idx = (size_t)R * 128 + C;
                float v = acc[cb][rr] + bb;
                if (ADDBF) v += bf2f(addbf[idx]);
                if (DOELU) v = (v > 0.f) ? v : expm1f(v);
                if (OUTF32) ((float*)outv)[idx] = v;
                else        ((unsigned short*)outv)[idx] = f2bf(v);
            }
        }
    }
}

template<int DUAL, int DOELU, int OUTF32, int NOBIAS, int ADDBF>
__global__ __launch_bounds__(256)
void k_mm(const unsigned short* __restrict__ A, const unsigned short* __restrict__ A2,
          const short* __restrict__ Wp, const short* __restrict__ Wp2,
          const float* __restrict__ bias, const unsigned short* __restrict__ addbf,
          void* outv) {
    __shared__ short sMem[16384];
    gemm_body<DUAL, DOELU, OUTF32, NOBIAS, ADDBF>(blockIdx.x, A, A2, Wp, Wp2, bias,
                                                  addbf, outv, sMem, sMem + 8192);
}

// ---------------- mega1: scatter || skip1 || T1 ----------------
// scatter: col_idx from (src,dst,row_start,cursor)
// skip1:   S1 = ELU(hB@Wsk1+bsk1) -> S1s (bf16, d_out scratch)
// T1:      T1 = hB@Wneigh1 (no bias) -> B1

__global__ __launch_bounds__(256)
void k_mega1(const int* __restrict__ src, const int* __restrict__ dst,
             const int* __restrict__ row_start, int* __restrict__ cursor,
             int* __restrict__ col_idx,
             const unsigned short* __restrict__ hB, const short* __restrict__ wpk,
             const float* __restrict__ bsk1,
             unsigned short* __restrict__ S1s, unsigned short* __restrict__ T1out) {
    __shared__ short sMem[16384];
    int bid = blockIdx.x;
    if (bid < SB) {
        int e = bid * 256 + threadIdx.x;
        if (e < NE) {
            int d = dst[e];
            int slot = atomicAdd(&cursor[d], 1);
            col_idx[row_start[d] + slot] = src[e];
        }
    } else if (bid < SB + NT) {
        gemm_body<0, 1, 0, 0, 0>(bid - SB, hB, nullptr, wpk /*skip1*/, nullptr,
                                 bsk1, nullptr, S1s, sMem, sMem + 8192);
    } else {
        gemm_body<0, 0, 0, 1, 0>(bid - SB - NT, hB, nullptr, wpk + 3 * 16384 /*neigh1*/,
                                 nullptr, nullptr, nullptr, T1out, sMem, sMem + 8192);
    }
}

// ---------------- mega2: conv1 || skip2 ----------------
// conv1: X1 = ELU(hB@Wself1 + AG1 + bc) -> B2 in-place (AG1 lives in B2)
// skip2: HS = S1s@Wsk2 + bsk2 -> B1 (bf16)

__global__ __launch_bounds__(256)
void k_mega2(const unsigned short* __restrict__ hB, const unsigned short* __restrict__ S1s,
             const short* __restrict__ wpk, const float* __restrict__ bc,
             const float* __restrict__ bsk2, unsigned short* __restrict__ B2,
             unsigned short* __restrict__ B1) {
    __shared__ short sMem[16384];
    int bid = blockIdx.x;
    if (bid < NT) {
        gemm_body<0, 1, 0, 0, 1>(bid, hB, nullptr, wpk + 2 * 16384 /*self1*/, nullptr,
                                 bc, B2 /*AG1 elemwise*/, B2, sMem, sMem + 8192);
    } else {
        gemm_body<0, 0, 0, 0, 0>(bid - NT, S1s, nullptr, wpk + 1 * 16384 /*skip2*/, nullptr,
                                 bsk2, nullptr, B1, sMem, sMem + 8192);
    }
}

// ---------------- launch ----------------

extern "C" void kernel_launch(void* const* d_in, const int* in_sizes, int n_in,
                              void* d_out, int out_size, void* d_ws, size_t ws_size,
                              hipStream_t stream) {
    const float* h        = (const float*)d_in[0];
    const int*   src      = (const int*)d_in[1];
    const int*   dst      = (const int*)d_in[2];
    const float* W_skip1  = (const float*)d_in[3];
    const float* b_skip1  = (const float*)d_in[4];
    const float* W_skip2  = (const float*)d_in[5];
    const float* b_skip2  = (const float*)d_in[6];
    const float* W_self1  = (const float*)d_in[7];
    const float* W_neigh1 = (const float*)d_in[8];
    const float* b_conv1  = (const float*)d_in[9];
    const float* W_si1    = (const float*)d_in[10];
    const float* b_si1    = (const float*)d_in[11];
    const float* W_si2    = (const float*)d_in[12];
    const float* b_si2    = (const float*)d_in[13];
    const float* W_self2  = (const float*)d_in[14];
    const float* W_neigh2 = (const float*)d_in[15];
    const float* b_conv2  = (const float*)d_in[16];
    float* out = (float*)d_out;

    char* ws = (char*)d_ws;
    int* deg       = (int*)ws;            // [50048]
    int* cursor    = deg + 50048;         // [50048]
    int* row_start = deg + 100096;        // [50001] (padded to 150208)
    int* partials  = deg + 150208;        // [64]
    int* col_idx   = deg + 150272;        // [800000] -> ends at byte 3801088
    short* wpk          = (short*)(ws + 3801088);            // 8 x 16384 bf16
    unsigned short* hB  = (unsigned short*)(ws + 4063232);   // h -> X3
    unsigned short* B1  = (unsigned short*)(ws + 16863232);  // T1 -> HS
    unsigned short* B2  = (unsigned short*)(ws + 29663232);  // AG1 -> X1 -> AG2
    unsigned short* S1s = (unsigned short*)d_out;            // S1 -> Y1 (bf16 scratch)

    hipMemsetAsync(ws, 0, 100096 * sizeof(int), stream);

    // cvt | hist | packW
    k_prep<<<6258, 256, 0, stream>>>(h, hB, dst, deg,
                                     W_skip1, W_skip2, W_self1, W_neigh1,
                                     W_si1, W_si2, W_self2, W_neigh2, wpk);
    k_scan_part<<<49, 1024, 0, stream>>>(deg, partials);
    k_scan_top<<<1, 64, 0, stream>>>(partials, row_start, 49);
    k_scan_final<<<49, 1024, 0, stream>>>(deg, partials, row_start);

    // scatter || skip1 || T1
    k_mega1<<<SB + 2 * NT, 256, 0, stream>>>(src, dst, row_start, cursor, col_idx,
                                             hB, wpk, b_skip1, S1s, B1);

    // AG1 = agg(T1) -> B2
    k_agg<<<12500, 256, 0, stream>>>(B1, row_start, col_idx, B2);

    // conv1 (single GEMM + elemwise AG1, in-place B2) || skip2 (S1s -> B1 as HS)
    k_mega2<<<2 * NT, 256, 0, stream>>>(hB, S1s, wpk, b_conv1, b_skip2, B2, B1);

    // si1: Y1 = ELU(X1@Wsi1+b) -> S1s
    k_mm<0, 1, 0, 0, 0><<<NT, 256, 0, stream>>>(B2, nullptr, wpk + 4 * 16384, nullptr,
                                                b_si1, nullptr, S1s);
    // si2: X3 = ELU(Y1@Wsi2+b) -> hB
    k_mm<0, 1, 0, 0, 0><<<NT, 256, 0, stream>>>(S1s, nullptr, wpk + 5 * 16384, nullptr,
                                                b_si2, nullptr, hB);

    // AG2 = agg(X3) -> B2
    k_agg<<<12500, 256, 0, stream>>>(hB, row_start, col_idx, B2);

    // conv2 dual + bias + HS residual -> f32 out
    k_mm<1, 0, 1, 0, 1><<<NT, 256, 0, stream>>>(hB, B2, wpk + 6 * 16384, wpk + 7 * 16384,
                                                b_conv2, B1, out);
}